// Round 23
// baseline (224.932 us; speedup 1.0000x reference)
//
#include <hip/hip_runtime.h>

// ---------------------------------------------------------------------------
// MalConv fused: GEMM M=16000, K=4000, N=256 (W1||W2 col-interleaved) in bf16
// MFMA 16x16x32, lane-local GLU+relu+segmented-max epilogue, then tiny FC.
//
// Round-25 = ALL-LDS inner loop. r13/r17/r22 all sit at 90-94us with every
// pipe <15% busy; per-kt ~1766cyc vs ~460 modeled. Unifying theory: vmcnt is
// a single in-order counter — the inner loop's wait-for-B sits behind cold
// x/HBM loads (r13/r17: scalar x; r22: the 32 staging gll4s) in the SAME
// queue, exposing ~HBM latency per step. Additionally x streaming (~4MB/XCD)
// evicts Bblk from the 4MB L2, so B waits are L3-class.
// Fix: ZERO global loads in the inner loop. Per 4-kt superphase, stage BOTH
// x (16x gll4) and B (16x gll16) into double-buffered LDS; one barrier per
// superphase drains. Steps read only LDS (lgkmcnt domain):
//   xs b32 -> embb gather b128 -> Bs b128 -> 16 MFMA.
//  * Bblk REPACKED [kt][quad][col256][8ch] so the lane-linear async write
//    lands in fragment order; Bs ds_read_b128 is 2-way-bank (free, m136).
//  * xs rows padded to 66 ints (gll dest stays lane-linear within a row;
//    padding only shifts row starts) to cut the 4-way b32 conflict.
//  * LDS 45KB (embb 4.1K + xs 8.4K + Bs 32K) -> 3 blocks/CU.
//  * 31 superphases x 4kt = kt 0..123; tail kt=124 reads global once.
//  * Unchanged (HW-verified r13/r17, absmax 0.03125): 1000x64 grid, 64x64
//    tile, interleaved-col GLU pairing, XCD remap, epilogue, atomicMax, fc.
// ---------------------------------------------------------------------------

typedef __attribute__((ext_vector_type(8))) short short8;
typedef __attribute__((ext_vector_type(4))) float f32x4;

__device__ __forceinline__ unsigned short f2b(float f) {
    union { float f; unsigned u; } un;
    un.f = f;
    unsigned u = un.u;
    return (unsigned short)((u + 0x7FFFu + ((u >> 16) & 1u)) >> 16);  // RNE
}

__device__ __forceinline__ void gll4(const int* g, void* l) {
    __builtin_amdgcn_global_load_lds(
        (const __attribute__((address_space(1))) void*)g,
        (__attribute__((address_space(3))) void*)l, 4, 0, 0);
}
__device__ __forceinline__ void gll16(const unsigned short* g, void* l) {
    __builtin_amdgcn_global_load_lds(
        (const __attribute__((address_space(1))) void*)g,
        (__attribute__((address_space(3))) void*)l, 16, 0, 0);
}

#define KT_COUNT 125                              // K = 4000 = 125 * 32
#define WS_BBLK_BYTES (KT_COUNT * 4 * 256 * 8 * 2)  // 2,048,000 B bf16 weights
#define WS_MWS_OFF WS_BBLK_BYTES                  // 8*128 f32 max accumulator

// Pack W1,W2 (fp32 [128][8][500]) -> bf16 Bblk[kt][g][c][ch] (g = k-subpos,
// c = INTERLEAVED col: c=grp*32+s; s<16 -> W1[grp*16+s], else W2[...]).
// Thread u = kt*256 + c: reads 8 float4 (contiguous k), writes 4x16B at
// stride 4KB — coalesced across threads. Also zero-inits m_ws.
__global__ __launch_bounds__(256) void prep_weights(
        const float* __restrict__ W1, const float* __restrict__ W2,
        unsigned short* __restrict__ Bblk, float* __restrict__ m_ws) {
    int u  = blockIdx.x * 256 + threadIdx.x;      // 0..31999
    int kt = u >> 8;                              // 0..124
    int c  = u & 255;
    int grp = c >> 5, s = c & 31;
    const float* W = (s < 16) ? W1 : W2;
    int oo = grp * 16 + (s & 15);                 // 0..127
    unsigned short v[4][8];
#pragma unroll
    for (int ch = 0; ch < 8; ++ch) {
        float4 w4 = *(const float4*)&W[oo * 4000 + ch * 500 + kt * 4];
        v[0][ch] = f2b(w4.x); v[1][ch] = f2b(w4.y);
        v[2][ch] = f2b(w4.z); v[3][ch] = f2b(w4.w);
    }
#pragma unroll
    for (int g = 0; g < 4; ++g) {
        uint4 pack;
        pack.x = (unsigned)v[g][0] | ((unsigned)v[g][1] << 16);
        pack.y = (unsigned)v[g][2] | ((unsigned)v[g][3] << 16);
        pack.z = (unsigned)v[g][4] | ((unsigned)v[g][5] << 16);
        pack.w = (unsigned)v[g][6] | ((unsigned)v[g][7] << 16);
        *(uint4*)&Bblk[kt * 8192 + g * 2048 + c * 8] = pack;
    }
    if (blockIdx.x < 4) m_ws[blockIdx.x * 256 + threadIdx.x] = 0.f;
}

// Main fused kernel: 1000 blocks x 64 threads (one wave). Work item
// w = mt*4 + nq: rows mt*64..+63, interleaved cols nq*64..+63.
__global__ __launch_bounds__(64, 1) void malconv_main(
        const int* __restrict__ x, const float* __restrict__ emb,
        const float* __restrict__ b1, const float* __restrict__ b2,
        const unsigned short* __restrict__ Bblk, float* __restrict__ m_ws) {
    __shared__ __align__(16) unsigned short embb[257 * 8];       // 4112 B
    __shared__ __align__(16) int xs[2][16][66];                  // 8448 B
    __shared__ __align__(16) unsigned short Bs[2][4][4][64][8];  // 32768 B

    const int t = threadIdx.x;
    for (int e = t; e < 257 * 8; e += 64) embb[e] = f2b(emb[e]);

    // XCD-chunked remap: the 4 nq tiles of an m-tile sit 8 apart in
    // blockIdx -> same XCD under round-robin dispatch -> x/Bblk L2 reuse.
    const int w  = (blockIdx.x & 7) * 125 + (blockIdx.x >> 3);
    const int mt = w >> 2, nq = w & 3;
    const int m0 = mt * 64;

    const int quad = t >> 4, l16 = t & 15;

    // staging sources (per-lane): x row m0+t; B col nq*64+t.
    const int* xsrc = x + (m0 + t) * 500;
    const unsigned short* bsrc = Bblk + (nq * 64 + t) * 8;

    // Stage superphase S (kt 4S..4S+3) into buffer S&1. All async; no dest
    // registers -> unsinkable; drained by the barrier at superphase end.
    auto stage = [&](int S) {
        const int buf = S & 1;
#pragma unroll
        for (int p = 0; p < 16; ++p)                       // x pos 16S+p
            gll4(xsrc + S * 16 + p, (void*)&xs[buf][p][0]);
#pragma unroll
        for (int s = 0; s < 4; ++s)                        // kt slot
#pragma unroll
            for (int j = 0; j < 4; ++j)                    // quad group
                gll16(bsrc + (4 * S + s) * 8192 + j * 2048,
                      (void*)&Bs[buf][s][j][0][0]);
    };

    f32x4 acc[4][4];
#pragma unroll
    for (int mi = 0; mi < 4; ++mi)
#pragma unroll
        for (int ni = 0; ni < 4; ++ni) {
            f32x4 z = {0.f, 0.f, 0.f, 0.f};
            acc[mi][ni] = z;
        }

    stage(0);
    __syncthreads();   // embb + stage(0) ready

    // One kt from LDS only: xs b32 -> embb gather b128 -> Bs b128 -> MFMA.
    auto step = [&](int s, int buf) {
        int xv[4];
        short8 af[4], bf[4];
#pragma unroll
        for (int mi = 0; mi < 4; ++mi)
            xv[mi] = xs[buf][s * 4 + quad][mi * 16 + l16];
#pragma unroll
        for (int ni = 0; ni < 4; ++ni)
            bf[ni] = *(const short8*)&Bs[buf][s][quad][ni * 16 + l16][0];
#pragma unroll
        for (int mi = 0; mi < 4; ++mi)
            af[mi] = *(const short8*)&embb[xv[mi] * 8];
#pragma unroll
        for (int mi = 0; mi < 4; ++mi)
#pragma unroll
            for (int ni = 0; ni < 4; ++ni)
                acc[mi][ni] = __builtin_amdgcn_mfma_f32_16x16x32_bf16(
                    af[mi], bf[ni], acc[mi][ni], 0, 0, 0);
    };

    // 31 superphases cover kt 0..123; stage(S+1) in flight during S.
    for (int S = 0; S < 31; ++S) {
        if (S < 30) stage(S + 1);
        const int buf = S & 1;
        step(0, buf); step(1, buf); step(2, buf); step(3, buf);
        __syncthreads();              // drain stage(S+1), release buf
    }
    // tail kt=124 (k pos 496..499): single global round-trip at the end.
    {
        int xv[4];
        short8 af[4], bf[4];
#pragma unroll
        for (int mi = 0; mi < 4; ++mi)
            xv[mi] = x[(m0 + mi * 16 + l16) * 500 + 496 + quad];
#pragma unroll
        for (int ni = 0; ni < 4; ++ni)
            bf[ni] = *(const short8*)(Bblk + 124 * 8192 + quad * 2048 +
                                      (nq * 64 + ni * 16 + l16) * 8);
#pragma unroll
        for (int mi = 0; mi < 4; ++mi)
            af[mi] = *(const short8*)&embb[xv[mi] * 8];
#pragma unroll
        for (int mi = 0; mi < 4; ++mi)
#pragma unroll
            for (int ni = 0; ni < 4; ++ni)
                acc[mi][ni] = __builtin_amdgcn_mfma_f32_16x16x32_bf16(
                    af[mi], bf[ni], acc[mi][ni], 0, 0, 0);
    }

    // ---- wave-local epilogue: GLU + relu + segmented max ----
    // pair p: g1 = acc[mi][2p] (W1 out j), g2 = acc[mi][2p+1] (W2 out j),
    // j = nq*32 + p*16 + l16.
    const int b0i = m0 / 2000;
    const int bsplit = (b0i + 1) * 2000;          // first patch of next batch
    const bool crosses = (m0 + 63) >= bsplit;
#pragma unroll
    for (int p = 0; p < 2; ++p) {
        const int j = nq * 32 + p * 16 + l16;
        const float bb1 = b1[j], bb2 = b2[j];
        float mx0 = 0.f, mx1 = 0.f;               // h >= 0 always
#pragma unroll
        for (int mi = 0; mi < 4; ++mi)
#pragma unroll
            for (int r = 0; r < 4; ++r) {
                int row = m0 + mi * 16 + quad * 4 + r;
                float g1 = acc[mi][2 * p][r] + bb1;
                float g2 = acc[mi][2 * p + 1][r] + bb2;
                float h = fmaxf(g1 / (1.f + __expf(-g2)), 0.f);
                if (row >= bsplit) mx1 = fmaxf(mx1, h);
                else               mx0 = fmaxf(mx0, h);
            }
        // reduce over quad (lanes with same l16)
        mx0 = fmaxf(mx0, __shfl_xor(mx0, 16));
        mx0 = fmaxf(mx0, __shfl_xor(mx0, 32));
        mx1 = fmaxf(mx1, __shfl_xor(mx1, 16));
        mx1 = fmaxf(mx1, __shfl_xor(mx1, 32));
        if (quad == 0) {
            // nonneg floats: int compare == float compare
            atomicMax((int*)&m_ws[b0i * 128 + j], __float_as_int(mx0));
            if (crosses)
                atomicMax((int*)&m_ws[(b0i + 1) * 128 + j], __float_as_int(mx1));
        }
    }
}

// out[b][j] = sum_o m_ws[b][o] * fcW[j][o] + fcb[j]   (16 outputs)
__global__ void fc_kernel(const float* __restrict__ m_ws,
                          const float* __restrict__ fcW,
                          const float* __restrict__ fcb,
                          float* __restrict__ out) {
    int t = threadIdx.x;
    if (t < 16) {
        int b = t >> 1, j = t & 1;
        float s = 0.f;
        for (int o = 0; o < 128; ++o) s += m_ws[b * 128 + o] * fcW[j * 128 + o];
        out[t] = s + fcb[j];
    }
}

extern "C" void kernel_launch(void* const* d_in, const int* in_sizes, int n_in,
                              void* d_out, int out_size, void* d_ws, size_t ws_size,
                              hipStream_t stream) {
    const int*   x   = (const int*)d_in[0];     // [8, 1e6] values 0..256
    const float* emb = (const float*)d_in[1];   // [257, 8]
    const float* W1  = (const float*)d_in[2];   // [128, 8, 500]
    const float* b1  = (const float*)d_in[3];   // [128]
    const float* W2  = (const float*)d_in[4];   // [128, 8, 500]
    const float* b2  = (const float*)d_in[5];   // [128]
    const float* fcW = (const float*)d_in[6];   // [2, 128]
    const float* fcb = (const float*)d_in[7];   // [2]
    float* out = (float*)d_out;                 // [8, 2]

    unsigned short* Bblk = (unsigned short*)d_ws;
    float* m_ws = (float*)((char*)d_ws + WS_MWS_OFF);

    prep_weights<<<125, 256, 0, stream>>>(W1, W2, Bblk, m_ws);
    malconv_main<<<1000, 64, 0, stream>>>(x, emb, b1, b2, Bblk, m_ws);
    fc_kernel<<<1, 64, 0, stream>>>(m_ws, fcW, fcb, out);
}